// Round 2
// baseline (207.648 us; speedup 1.0000x reference)
//
#include <hip/hip_runtime.h>
#include <math.h>

#define NH 512
#define NM 160
#define BROWS 65536
#define BM 128
#define BK 64
#define NCHUNK (NH / BK)   // 8

typedef __attribute__((ext_vector_type(8))) __bf16 bf16x8;
typedef __attribute__((ext_vector_type(4))) __bf16 bf16x4;
typedef __attribute__((ext_vector_type(4))) float  f32x4;

// ---------------- kernel 1: M -> bf16, and ||M_j||^2 ----------------
__global__ __launch_bounds__(64) void mprep_kernel(const float* __restrict__ M,
                                                   __bf16* __restrict__ Mb,
                                                   float* __restrict__ mnorm) {
    const int m = blockIdx.x;          // 160 blocks, one wave each
    const int l = threadIdx.x;
    const float* row = M + (size_t)m * NH;
    float s = 0.f;
#pragma unroll
    for (int k = 0; k < 2; ++k) {
        float4 v = *reinterpret_cast<const float4*>(row + 4 * l + 256 * k);
        s = fmaf(v.x, v.x, fmaf(v.y, v.y, fmaf(v.z, v.z, fmaf(v.w, v.w, s))));
        bf16x4 b = {(__bf16)v.x, (__bf16)v.y, (__bf16)v.z, (__bf16)v.w};
        *reinterpret_cast<bf16x4*>(Mb + (size_t)m * NH + 4 * l + 256 * k) = b;
    }
#pragma unroll
    for (int off = 32; off > 0; off >>= 1) s += __shfl_down(s, off);
    if (l == 0) mnorm[m] = s;
}

// ---------------- kernel 2: fused bf16-MFMA GEMM + transform + masked reduce ----
// 256 threads = 4 waves. Wave w owns rows [32w,32w+32) of the 128-row block,
// all 160 motifs as 10 col-tiles of 16. Motif class of (ct*16+c) == ct.
__global__ __launch_bounds__(256, 2) void motif_main(
    const float* __restrict__ z, const __bf16* __restrict__ Mb,
    const int* __restrict__ y, const float* __restrict__ mnorm,
    float* __restrict__ loss_sum) {
    // row stride 64 bf16 = 128 B = 32 banks -> XOR-swizzle 16B slots by row&7
    __shared__ __align__(16) __bf16 zs[BM * BK];
    __shared__ __align__(16) __bf16 ms[NM * BK];
    __shared__ float znorm[BM];
    __shared__ float red[256];

    const int tid = threadIdx.x;
    const int w   = tid >> 6;          // wave 0..3
    const int l   = tid & 63;
    const int row0 = blockIdx.x * BM;

    f32x4 acc[2][10];
#pragma unroll
    for (int rt = 0; rt < 2; ++rt)
#pragma unroll
        for (int ct = 0; ct < 10; ++ct) acc[rt][ct] = (f32x4){0.f, 0.f, 0.f, 0.f};
    float zp[8] = {0.f, 0.f, 0.f, 0.f, 0.f, 0.f, 0.f, 0.f};

#pragma unroll 1
    for (int ch = 0; ch < NCHUNK; ++ch) {
        const int k0 = ch * BK;
        // stage z: 128 rows x 16 float4 = 2048 float4, 8/thread, coalesced
#pragma unroll
        for (int s = 0; s < 8; ++s) {
            const int idx = tid + 256 * s;
            const int r = idx >> 4, c4 = idx & 15;
            float4 v = *reinterpret_cast<const float4*>(
                z + (size_t)(row0 + r) * NH + k0 + c4 * 4);
            zp[s] = fmaf(v.x, v.x, fmaf(v.y, v.y, fmaf(v.z, v.z, fmaf(v.w, v.w, zp[s]))));
            const int slot = (c4 >> 1) ^ (r & 7);
            bf16x4 b = {(__bf16)v.x, (__bf16)v.y, (__bf16)v.z, (__bf16)v.w};
            *reinterpret_cast<bf16x4*>(&zs[r * BK + slot * 8 + (c4 & 1) * 4]) = b;
        }
        // stage M (pre-converted bf16): 160 rows x 8 slots = 1280, 5/thread
#pragma unroll
        for (int s = 0; s < 5; ++s) {
            const int sidx = tid + 256 * s;
            const int r = sidx >> 3, sl = sidx & 7;
            bf16x8 v = *reinterpret_cast<const bf16x8*>(
                Mb + (size_t)r * NH + k0 + sl * 8);
            *reinterpret_cast<bf16x8*>(&ms[r * BK + (sl ^ (r & 7)) * 8]) = v;
        }
        __syncthreads();

        const int r16 = l & 15;
        const int kg  = l >> 4;        // k-group 0..3
#pragma unroll
        for (int q = 0; q < 2; ++q) {  // two K=32 halves of the BK=64 chunk
            const int slotk = q * 4 + kg;
            bf16x8 a[2], b[10];
#pragma unroll
            for (int rt = 0; rt < 2; ++rt) {
                const int r = w * 32 + rt * 16 + r16;
                a[rt] = *reinterpret_cast<const bf16x8*>(
                    &zs[r * BK + (slotk ^ (r & 7)) * 8]);
            }
#pragma unroll
            for (int ct = 0; ct < 10; ++ct) {
                const int r = ct * 16 + r16;
                b[ct] = *reinterpret_cast<const bf16x8*>(
                    &ms[r * BK + (slotk ^ (r & 7)) * 8]);
            }
#pragma unroll
            for (int rt = 0; rt < 2; ++rt)
#pragma unroll
                for (int ct = 0; ct < 10; ++ct)
                    acc[rt][ct] = __builtin_amdgcn_mfma_f32_16x16x32_bf16(
                        a[rt], b[ct], acc[rt][ct], 0, 0, 0);
        }
        __syncthreads();
    }

    // finish ||z||^2: butterfly over the 16 lanes sharing (tid>>4); zp[s] is
    // the partial for row (tid>>4)+16s over cols {4*(tid&15)+[0,4)} all chunks
#pragma unroll
    for (int s = 0; s < 8; ++s) {
#pragma unroll
        for (int off = 1; off < 16; off <<= 1) zp[s] += __shfl_xor(zp[s], off);
    }
    if ((l & 15) == 0) {
#pragma unroll
        for (int s = 0; s < 8; ++s) znorm[(tid >> 4) + 16 * s] = zp[s];
    }
    __syncthreads();

    float mn[10];
#pragma unroll
    for (int ct = 0; ct < 10; ++ct) mn[ct] = mnorm[ct * 16 + (l & 15)];

    // D layout: col = ct*16 + (l&15), row = w*32 + rt*16 + (l>>4)*4 + rr
    float local = 0.f;
#pragma unroll
    for (int rt = 0; rt < 2; ++rt) {
#pragma unroll
        for (int rr = 0; rr < 4; ++rr) {
            const int row = w * 32 + rt * 16 + (l >> 4) * 4 + rr;
            const float nz = znorm[row];
            const int yr = y[row0 + row];
            float p = 0.f, t = 0.f;
#pragma unroll
            for (int ct = 0; ct < 10; ++ct) {
                float dist = nz + mn[ct] - 2.0f * acc[rt][ct][rr];
                float rat = (dist + 1.0f) / (dist + 1e-4f);
                float r2 = rat * rat;
                float sv = r2 * r2 * rat;      // r^5 == exp(log(r)/0.2)
                t += sv;
                p = (ct == yr) ? (p + sv) : p;
            }
            // sum across the 16 motifs within each col-tile (lanes l&15)
#pragma unroll
            for (int off = 1; off < 16; off <<= 1) {
                p += __shfl_xor(p, off);
                t += __shfl_xor(t, off);
            }
            if ((l & 15) == 0) local += logf(p / t);
        }
    }

    red[tid] = local;
    __syncthreads();
#pragma unroll 1
    for (int s = 128; s > 0; s >>= 1) {
        if (tid < s) red[tid] += red[tid + s];
        __syncthreads();
    }
    if (tid == 0) atomicAdd(loss_sum, red[0]);
}

// ---------------- kernel 3: finalize ----------------
__global__ void finalize_kernel(const float* __restrict__ loss_sum,
                                float* __restrict__ out) {
    out[0] = -loss_sum[0] * (1.0f / (float)BROWS);
}

extern "C" void kernel_launch(void* const* d_in, const int* in_sizes, int n_in,
                              void* d_out, int out_size, void* d_ws, size_t ws_size,
                              hipStream_t stream) {
    const float* z = (const float*)d_in[0];
    const float* M = (const float*)d_in[1];
    const int*   y = (const int*)d_in[2];
    float* out = (float*)d_out;

    // workspace layout: [0,160KB) M in bf16; then mnorm[160] f32; then loss_sum
    __bf16* Mb      = (__bf16*)d_ws;
    float*  mnorm   = (float*)((char*)d_ws + (size_t)NM * NH * sizeof(__bf16));
    float*  loss_sum = mnorm + NM;

    hipMemsetAsync(loss_sum, 0, sizeof(float), stream);
    mprep_kernel<<<NM, 64, 0, stream>>>(M, Mb, mnorm);
    motif_main<<<BROWS / BM, 256, 0, stream>>>(z, Mb, y, mnorm, loss_sum);
    finalize_kernel<<<1, 1, 0, stream>>>(loss_sum, out);
}